// Round 1
// baseline (387.734 us; speedup 1.0000x reference)
//
#include <hip/hip_runtime.h>
#include <math.h>

#define SEQ   2048
#define BATCH 32
#define HID   1024
#define CHUNK 16
#define NCHUNK (SEQ / CHUNK)   // 128 chunks per batch

// ---------------------------------------------------------------------------
// Kernel A: per (b, s-chunk) partial online-softmax attention.
// One block = 256 threads; thread t owns hidden columns h = 4t..4t+3.
// The 16 rows of the chunk live in registers (16 x float4 = 64 VGPR/thread),
// so rnn_out is read from HBM exactly once.
// ---------------------------------------------------------------------------
__global__ __launch_bounds__(256) void attn_partial(
    const float* __restrict__ rnn_out,   // [S, B, H]
    const float* __restrict__ state,     // [2, 2, B, H/2]
    float* __restrict__ o_part,          // [B*NCHUNK, H]
    float* __restrict__ m_part,          // [B*NCHUNK]
    float* __restrict__ l_part)          // [B*NCHUNK]
{
    const int blk   = blockIdx.x;        // b * NCHUNK + chunk
    const int b     = blk / NCHUNK;
    const int chunk = blk % NCHUNK;
    const int t     = threadIdx.x;       // 0..255
    const int h     = t * 4;

    // merged[b][h] = state[1][h/512][b][h%512]  (concat of the two direction c-states)
    const int j = h >> 9;                // 0 or 1 (4-aligned, never straddles 512)
    const int k = h & 511;
    const float4 mrg = *(const float4*)(state + (size_t)((2 + j) * BATCH + b) * 512 + k);

    const int s0 = chunk * CHUNK;
    const float* base = rnn_out + ((size_t)s0 * BATCH + b) * HID + h;
    const size_t row_stride = (size_t)BATCH * HID;   // floats between consecutive s

    // Load 16 rows (this block's float4 slice) + dot partials
    float4 rows[CHUNK];
    float  sc[CHUNK];
    #pragma unroll
    for (int i = 0; i < CHUNK; ++i) {
        rows[i] = *(const float4*)(base + (size_t)i * row_stride);
        sc[i] = rows[i].x * mrg.x + rows[i].y * mrg.y
              + rows[i].z * mrg.z + rows[i].w * mrg.w;
    }

    // Block-wide reduction of all 16 dot products (wave shuffle -> LDS -> sum).
    #pragma unroll
    for (int i = 0; i < CHUNK; ++i) {
        float v = sc[i];
        #pragma unroll
        for (int off = 32; off > 0; off >>= 1)
            v += __shfl_down(v, off, 64);
        sc[i] = v;                       // full wave sum valid on lane 0
    }
    __shared__ float red[4][CHUNK];
    const int lane = t & 63, wave = t >> 6;
    if (lane == 0) {
        #pragma unroll
        for (int i = 0; i < CHUNK; ++i) red[wave][i] = sc[i];
    }
    __syncthreads();
    #pragma unroll
    for (int i = 0; i < CHUNK; ++i)
        sc[i] = red[0][i] + red[1][i] + red[2][i] + red[3][i];

    // Chunk-local softmax partial
    float m = -INFINITY;
    #pragma unroll
    for (int i = 0; i < CHUNK; ++i) m = fmaxf(m, sc[i]);
    float l = 0.f;
    float4 acc = make_float4(0.f, 0.f, 0.f, 0.f);
    #pragma unroll
    for (int i = 0; i < CHUNK; ++i) {
        const float w = expf(sc[i] - m);
        l += w;
        acc.x += w * rows[i].x;
        acc.y += w * rows[i].y;
        acc.z += w * rows[i].z;
        acc.w += w * rows[i].w;
    }

    *(float4*)(o_part + (size_t)blk * HID + h) = acc;
    if (t == 0) { m_part[blk] = m; l_part[blk] = l; }
}

// ---------------------------------------------------------------------------
// Kernel B: combine the 128 chunk-partials per batch.
// Grid = B * (HID/64) = 512 blocks so HBM stays saturated (16 MB read).
// Block: 256 threads = 16 float4-columns x 16 chunk-ways; LDS tree at the end.
// ---------------------------------------------------------------------------
__global__ __launch_bounds__(256) void attn_combine(
    const float* __restrict__ o_part,    // [B*NCHUNK, H]
    const float* __restrict__ m_part,
    const float* __restrict__ l_part,
    float* __restrict__ out)             // [B, H] (== [B, H, 1] flat)
{
    const int b  = blockIdx.x / (HID / 64);
    const int hs = blockIdx.x % (HID / 64);      // 64-column slice
    const int t  = threadIdx.x;
    const int cg  = t & 15;                      // column group: 4 floats
    const int way = t >> 4;                      // 16 chunk-ways
    const int h  = hs * 64 + cg * 4;

    // Global softmax stats (broadcast scalar loads; all threads redundant).
    const float* mp = m_part + b * NCHUNK;
    const float* lp = l_part + b * NCHUNK;
    float M = -INFINITY;
    for (int c = 0; c < NCHUNK; ++c) M = fmaxf(M, mp[c]);
    float L = 0.f;
    for (int c = 0; c < NCHUNK; ++c) L += lp[c] * expf(mp[c] - M);
    const float invL = 1.f / L;

    float4 acc = make_float4(0.f, 0.f, 0.f, 0.f);
    for (int c = way; c < NCHUNK; c += 16) {
        const float w = expf(mp[c] - M) * invL;
        const float4 o = *(const float4*)(o_part + (size_t)(b * NCHUNK + c) * HID + h);
        acc.x += w * o.x; acc.y += w * o.y; acc.z += w * o.z; acc.w += w * o.w;
    }

    __shared__ float4 red[16][16];               // [way][cg]
    red[way][cg] = acc;
    __syncthreads();
    if (way == 0) {
        float4 r = red[0][cg];
        #pragma unroll
        for (int wy = 1; wy < 16; ++wy) {
            const float4 o = red[wy][cg];
            r.x += o.x; r.y += o.y; r.z += o.z; r.w += o.w;
        }
        *(float4*)(out + (size_t)b * HID + h) = r;
    }
}

extern "C" void kernel_launch(void* const* d_in, const int* in_sizes, int n_in,
                              void* d_out, int out_size, void* d_ws, size_t ws_size,
                              hipStream_t stream) {
    const float* rnn_out = (const float*)d_in[0];   // [2048, 32, 1024] f32
    const float* state   = (const float*)d_in[1];   // [2, 2, 32, 512]  f32
    float* out = (float*)d_out;                     // [32, 1024, 1]    f32

    // workspace layout (16 MB + 32 KB, 16B-aligned offsets)
    float* o_part = (float*)d_ws;                                   // 16 MiB
    float* m_part = (float*)((char*)d_ws + (size_t)BATCH * NCHUNK * HID * 4);
    float* l_part = m_part + BATCH * NCHUNK;

    attn_partial<<<BATCH * NCHUNK, 256, 0, stream>>>(rnn_out, state, o_part, m_part, l_part);
    attn_combine<<<BATCH * (HID / 64), 256, 0, stream>>>(o_part, m_part, l_part, out);
}

// Round 2
// 373.506 us; speedup vs baseline: 1.0381x; 1.0381x over previous
//
#include <hip/hip_runtime.h>
#include <math.h>

#define SEQ   2048
#define BATCH 32
#define HID   1024
#define RPW   16                        // seq rows per wave
#define WPB   4                         // waves per block (independent)
#define WAVES_PER_B  (SEQ / RPW)        // 128 partials per batch
#define BLOCKS_PER_B (WAVES_PER_B / WPB) // 32

// ---------------------------------------------------------------------------
// Kernel A: wave-autonomous flash partial. No LDS, no barriers.
// Wave handles batch b, rows s0..s0+15. Lane owns columns {4*(lane+64j)} j<4.
// Dot product reduced with a 6-step shuffle butterfly (score wave-uniform),
// online-softmax (m,l,acc) per wave; next row prefetched before the reduce.
// ---------------------------------------------------------------------------
__global__ __launch_bounds__(256) void attn_partial(
    const float* __restrict__ rnn_out,   // [S, B, H]
    const float* __restrict__ state,     // [2, 2, B, H/2]
    float* __restrict__ o_part,          // [B*WAVES_PER_B, H]
    float* __restrict__ m_part,          // [B*WAVES_PER_B]
    float* __restrict__ l_part)          // [B*WAVES_PER_B]
{
    const int b     = blockIdx.x / BLOCKS_PER_B;
    const int slice = blockIdx.x % BLOCKS_PER_B;
    const int lane  = threadIdx.x & 63;
    const int wav   = threadIdx.x >> 6;
    const int wid   = slice * WPB + wav;       // 0..127
    const int s0    = wid * RPW;

    // merged[b][h] = state[1][h/512][b][h%512]; lane's 4 float4 slices
    float4 mrg[4];
    #pragma unroll
    for (int j = 0; j < 4; ++j) {
        const int h   = 4 * (lane + 64 * j);
        const int dir = h >> 9;
        const int k   = h & 511;
        mrg[j] = *(const float4*)(state + ((size_t)(2 + dir) * BATCH + b) * 512 + k);
    }

    const size_t row_stride = (size_t)BATCH * HID;
    const float* base = rnn_out + ((size_t)s0 * BATCH + b) * HID + 4 * lane;

    float4 cur[4], nxt[4];
    #pragma unroll
    for (int j = 0; j < 4; ++j)
        cur[j] = *(const float4*)(base + 256 * j);

    float  m = -INFINITY, l = 0.f;
    float4 acc[4];
    #pragma unroll
    for (int j = 0; j < 4; ++j) acc[j] = make_float4(0.f, 0.f, 0.f, 0.f);

    #pragma unroll
    for (int i = 0; i < RPW; ++i) {
        // prefetch next row while we reduce the current one
        if (i + 1 < RPW) {
            const float* nb = base + (size_t)(i + 1) * row_stride;
            #pragma unroll
            for (int j = 0; j < 4; ++j)
                nxt[j] = *(const float4*)(nb + 256 * j);
        }

        float d = 0.f;
        #pragma unroll
        for (int j = 0; j < 4; ++j)
            d += cur[j].x * mrg[j].x + cur[j].y * mrg[j].y
               + cur[j].z * mrg[j].z + cur[j].w * mrg[j].w;
        #pragma unroll
        for (int off = 1; off < 64; off <<= 1)
            d += __shfl_xor(d, off, 64);       // all lanes hold the full dot

        // online softmax update; d is wave-uniform -> branch is divergence-free
        if (d > m) {
            const float alpha = __expf(m - d); // exp(-inf)=0 on first row
            l *= alpha;
            #pragma unroll
            for (int j = 0; j < 4; ++j) {
                acc[j].x *= alpha; acc[j].y *= alpha;
                acc[j].z *= alpha; acc[j].w *= alpha;
            }
            m = d;
        }
        const float p = __expf(d - m);
        l += p;
        #pragma unroll
        for (int j = 0; j < 4; ++j) {
            acc[j].x += p * cur[j].x; acc[j].y += p * cur[j].y;
            acc[j].z += p * cur[j].z; acc[j].w += p * cur[j].w;
        }
        #pragma unroll
        for (int j = 0; j < 4; ++j) cur[j] = nxt[j];
    }

    float* op = o_part + (size_t)(b * WAVES_PER_B + wid) * HID + 4 * lane;
    #pragma unroll
    for (int j = 0; j < 4; ++j) *(float4*)(op + 256 * j) = acc[j];
    if (lane == 0) {
        m_part[b * WAVES_PER_B + wid] = m;
        l_part[b * WAVES_PER_B + wid] = l;
    }
}

// ---------------------------------------------------------------------------
// Kernel B: combine the 128 wave-partials per batch (16 MB read).
// Grid = B * (HID/64) = 512 blocks; 16 chunk-ways x 16 float4-cols per block.
// ---------------------------------------------------------------------------
#define NCH WAVES_PER_B   // 128
__global__ __launch_bounds__(256) void attn_combine(
    const float* __restrict__ o_part,    // [B*NCH, H]
    const float* __restrict__ m_part,
    const float* __restrict__ l_part,
    float* __restrict__ out)             // [B, H]
{
    const int b  = blockIdx.x / (HID / 64);
    const int hs = blockIdx.x % (HID / 64);
    const int t  = threadIdx.x;
    const int cg  = t & 15;
    const int way = t >> 4;
    const int h  = hs * 64 + cg * 4;

    const float* mp = m_part + b * NCH;
    const float* lp = l_part + b * NCH;
    float M = -INFINITY;
    for (int c = 0; c < NCH; ++c) M = fmaxf(M, mp[c]);
    float L = 0.f;
    for (int c = 0; c < NCH; ++c) L += lp[c] * __expf(mp[c] - M);
    const float invL = 1.f / L;

    float4 acc = make_float4(0.f, 0.f, 0.f, 0.f);
    for (int c = way; c < NCH; c += 16) {
        const float w = __expf(mp[c] - M) * invL;
        const float4 o = *(const float4*)(o_part + (size_t)(b * NCH + c) * HID + h);
        acc.x += w * o.x; acc.y += w * o.y; acc.z += w * o.z; acc.w += w * o.w;
    }

    __shared__ float4 red[16][16];
    red[way][cg] = acc;
    __syncthreads();
    if (way == 0) {
        float4 r = red[0][cg];
        #pragma unroll
        for (int wy = 1; wy < 16; ++wy) {
            const float4 o = red[wy][cg];
            r.x += o.x; r.y += o.y; r.z += o.z; r.w += o.w;
        }
        *(float4*)(out + (size_t)b * HID + h) = r;
    }
}

extern "C" void kernel_launch(void* const* d_in, const int* in_sizes, int n_in,
                              void* d_out, int out_size, void* d_ws, size_t ws_size,
                              hipStream_t stream) {
    const float* rnn_out = (const float*)d_in[0];   // [2048, 32, 1024] f32
    const float* state   = (const float*)d_in[1];   // [2, 2, 32, 512]  f32
    float* out = (float*)d_out;                     // [32, 1024, 1]    f32

    float* o_part = (float*)d_ws;                                        // 16 MiB
    float* m_part = (float*)((char*)d_ws + (size_t)BATCH * NCH * HID * 4);
    float* l_part = m_part + BATCH * NCH;

    attn_partial<<<BATCH * BLOCKS_PER_B, 256, 0, stream>>>(rnn_out, state, o_part, m_part, l_part);
    attn_combine<<<BATCH * (HID / 64), 256, 0, stream>>>(o_part, m_part, l_part, out);
}

// Round 4
// 344.129 us; speedup vs baseline: 1.1267x; 1.0854x over previous
//
#include <hip/hip_runtime.h>
#include <math.h>

#define SEQ   2048
#define BATCH 32
#define HID   1024
#define RPW   32                        // seq rows per wave
#define WPB   4                         // waves per block (independent)
#define WAVES_PER_B  (SEQ / RPW)        // 64 partials per batch
#define BLOCKS_PER_B (WAVES_PER_B / WPB) // 16

// native vector type: __builtin_nontemporal_load accepts these (not HIP_vector_type)
typedef float vf4 __attribute__((ext_vector_type(4)));

// ---------------------------------------------------------------------------
// Kernel A: wave-autonomous flash partial. No LDS, no barriers.
// Wave handles batch b, rows s0..s0+31. Lane owns columns {4*(lane+64j)} j<4.
// Dot reduced with a 6-step shuffle butterfly (score becomes wave-uniform),
// single-exp online softmax, next-row prefetch keeps loads in flight.
// rnn_out loads are nontemporal (single-use; keep partials cache-resident).
// ---------------------------------------------------------------------------
__global__ __launch_bounds__(256) void attn_partial(
    const float* __restrict__ rnn_out,   // [S, B, H]
    const float* __restrict__ state,     // [2, 2, B, H/2]
    float* __restrict__ o_part,          // [B*WAVES_PER_B, H]
    float* __restrict__ m_part,          // [B*WAVES_PER_B]
    float* __restrict__ l_part)          // [B*WAVES_PER_B]
{
    const int b     = blockIdx.x / BLOCKS_PER_B;
    const int slice = blockIdx.x % BLOCKS_PER_B;
    const int lane  = threadIdx.x & 63;
    const int wav   = threadIdx.x >> 6;
    const int wid   = slice * WPB + wav;       // 0..63
    const int s0    = wid * RPW;

    // merged[b][h] = state[1][h/512][b][h%512]; lane's 4 vf4 slices
    vf4 mrg[4];
    #pragma unroll
    for (int j = 0; j < 4; ++j) {
        const int h   = 4 * (lane + 64 * j);
        const int dir = h >> 9;
        const int k   = h & 511;
        mrg[j] = *(const vf4*)(state + ((size_t)(2 + dir) * BATCH + b) * 512 + k);
    }

    const size_t row_stride = (size_t)BATCH * HID;
    const float* base = rnn_out + ((size_t)s0 * BATCH + b) * HID + 4 * lane;

    vf4 cur[4], nxt[4];
    #pragma unroll
    for (int j = 0; j < 4; ++j)
        cur[j] = __builtin_nontemporal_load((const vf4*)(base + 256 * j));

    float m = -INFINITY, l = 0.f;
    vf4 acc[4];
    #pragma unroll
    for (int j = 0; j < 4; ++j) acc[j] = (vf4)(0.f);

    for (int i = 0; i < RPW; ++i) {
        // prefetch next row while we reduce the current one
        if (i + 1 < RPW) {
            const float* nb = base + (size_t)(i + 1) * row_stride;
            #pragma unroll
            for (int j = 0; j < 4; ++j)
                nxt[j] = __builtin_nontemporal_load((const vf4*)(nb + 256 * j));
        }

        float d = 0.f;
        #pragma unroll
        for (int j = 0; j < 4; ++j) {
            const vf4 p = cur[j] * mrg[j];
            d += p.x + p.y + p.z + p.w;
        }
        #pragma unroll
        for (int off = 1; off < 64; off <<= 1)
            d += __shfl_xor(d, off, 64);       // all lanes hold the full dot

        // single-exp online update; d wave-uniform -> uniform scalar branch
        if (d > m) {
            const float alpha = __expf(m - d); // exp(-inf)=0 on first row
            l = l * alpha + 1.f;               // p == exp(d - d) == 1
            #pragma unroll
            for (int j = 0; j < 4; ++j)
                acc[j] = acc[j] * alpha + cur[j];
            m = d;
        } else {
            const float p = __expf(d - m);
            l += p;
            #pragma unroll
            for (int j = 0; j < 4; ++j)
                acc[j] += p * cur[j];
        }
        #pragma unroll
        for (int j = 0; j < 4; ++j) cur[j] = nxt[j];
    }

    float* op = o_part + (size_t)(b * WAVES_PER_B + wid) * HID + 4 * lane;
    #pragma unroll
    for (int j = 0; j < 4; ++j) *(vf4*)(op + 256 * j) = acc[j];
    if (lane == 0) {
        m_part[b * WAVES_PER_B + wid] = m;
        l_part[b * WAVES_PER_B + wid] = l;
    }
}

// ---------------------------------------------------------------------------
// Kernel B: combine the 64 wave-partials per batch (8 MB, mostly L2/L3-hit).
// Grid = B * (HID/64) = 512 blocks; 16 chunk-ways x 16 vf4-cols per block.
// ---------------------------------------------------------------------------
#define NCH WAVES_PER_B   // 64
__global__ __launch_bounds__(256) void attn_combine(
    const float* __restrict__ o_part,    // [B*NCH, H]
    const float* __restrict__ m_part,
    const float* __restrict__ l_part,
    float* __restrict__ out)             // [B, H]
{
    const int b  = blockIdx.x / (HID / 64);
    const int hs = blockIdx.x % (HID / 64);
    const int t  = threadIdx.x;
    const int cg  = t & 15;
    const int way = t >> 4;
    const int h  = hs * 64 + cg * 4;

    const float* mp = m_part + b * NCH;
    const float* lp = l_part + b * NCH;
    float M = -INFINITY;
    for (int c = 0; c < NCH; ++c) M = fmaxf(M, mp[c]);
    float L = 0.f;
    for (int c = 0; c < NCH; ++c) L += lp[c] * __expf(mp[c] - M);
    const float invL = 1.f / L;

    vf4 acc = (vf4)(0.f);
    for (int c = way; c < NCH; c += 16) {
        const float w = __expf(mp[c] - M) * invL;
        const vf4 o = *(const vf4*)(o_part + (size_t)(b * NCH + c) * HID + h);
        acc += w * o;
    }

    __shared__ vf4 red[16][16];
    red[way][cg] = acc;
    __syncthreads();
    if (way == 0) {
        vf4 r = red[0][cg];
        #pragma unroll
        for (int wy = 1; wy < 16; ++wy)
            r += red[wy][cg];
        *(vf4*)(out + (size_t)b * HID + h) = r;
    }
}

extern "C" void kernel_launch(void* const* d_in, const int* in_sizes, int n_in,
                              void* d_out, int out_size, void* d_ws, size_t ws_size,
                              hipStream_t stream) {
    const float* rnn_out = (const float*)d_in[0];   // [2048, 32, 1024] f32
    const float* state   = (const float*)d_in[1];   // [2, 2, 32, 512]  f32
    float* out = (float*)d_out;                     // [32, 1024, 1]    f32

    float* o_part = (float*)d_ws;                                        // 8 MiB
    float* m_part = (float*)((char*)d_ws + (size_t)BATCH * NCH * HID * 4);
    float* l_part = m_part + BATCH * NCH;

    attn_partial<<<BATCH * BLOCKS_PER_B, 256, 0, stream>>>(rnn_out, state, o_part, m_part, l_part);
    attn_combine<<<BATCH * (HID / 64), 256, 0, stream>>>(o_part, m_part, l_part, out);
}